// Round 2
// baseline (359.182 us; speedup 1.0000x reference)
//
#include <hip/hip_runtime.h>
#include <math.h>

#define NV   8
#define NC   32
#define ND   64
#define NH   64
#define NW   64
#define IMG  128

using f4 = __attribute__((ext_vector_type(4))) float;

// ---------------- Kernel 1: repack [V,C,Y,X] -> [V,Y,X,C] ----------------
__global__ __launch_bounds__(256) void repack_kernel(
    const float* __restrict__ in, float* __restrict__ out)
{
    __shared__ float tile[IMG][NC + 1];          // 128 x 33 floats, pad kills conflicts
    const int vy = blockIdx.x;                   // v*128 + y
    const int v  = vy >> 7;
    const int y  = vy & 127;
    const float* src = in + (size_t)v * NC * IMG * IMG + (size_t)y * IMG;

#pragma unroll
    for (int k = 0; k < NC * IMG; k += 256) {    // read coalesced along x
        const int flat = k + threadIdx.x;
        const int x = flat & (IMG - 1);
        const int c = flat >> 7;
        tile[x][c] = src[(size_t)c * IMG * IMG + x];
    }
    __syncthreads();

    float* dst = out + (size_t)vy * IMG * NC;    // [x][c] contiguous
#pragma unroll
    for (int k = 0; k < NC * IMG; k += 256) {    // write coalesced along c-then-x
        const int flat = k + threadIdx.x;
        const int c = flat & (NC - 1);
        const int x = flat >> 5;
        dst[flat] = tile[x][c];
    }
}

// ---------------- Kernel 2: back-projection, channel-last gathers ----------------
__global__ __launch_bounds__(256, 4) void backproj_cl_kernel(
    const float* __restrict__ imgs,    // [V, Y, X, C] channel-last (in d_ws)
    const float* __restrict__ angles,  // [V]
    float* __restrict__ out)           // [C, D, H, W]
{
    const int c4 = threadIdx.x & 7;    // channel quad: channels c4*4 .. c4*4+3
    const int w0 = threadIdx.x >> 3;   // 0..31 ; this thread does w0 and w0+32
    const int h  = blockIdx.x & 63;
    const int d  = blockIdx.x >> 6;

    const float step = 240.0f / 63.0f;

    // y side: depends only on d
    const float zd  = -120.0f + d * step;
    const float yf  = (zd * (1.0f / 120.0f) + 1.0f) * 63.5f;
    const float y0f = floorf(yf);
    const float wy1 = yf - y0f;
    const float wy0 = 1.0f - wy1;
    const int iy0 = (int)y0f;
    const int iy1 = iy0 + 1;
    const float fy0 = (iy0 >= 0 && iy0 < IMG) ? 1.0f : 0.0f;
    const float fy1 = (iy1 >= 0 && iy1 < IMG) ? 1.0f : 0.0f;
    const int r0 = min(max(iy0, 0), IMG - 1);
    const int r1 = min(max(iy1, 0), IMG - 1);

    const float yh = -120.0f + h * step;

    f4 acc[2];
    acc[0] = (f4)0.0f;
    acc[1] = (f4)0.0f;

#pragma unroll
    for (int v = 0; v < NV; ++v) {
        float s, c;
        sincosf(angles[v], &s, &c);
        const float sy = s * yh;

        const float* base0 = imgs + (((size_t)v * IMG + r0) * IMG) * NC + c4 * 4;
        const float* base1 = imgs + (((size_t)v * IMG + r1) * IMG) * NC + c4 * 4;

#pragma unroll
        for (int j = 0; j < 2; ++j) {
            const int w = w0 + j * 32;
            const float xw = -120.0f + w * step;
            const float u  = c * xw - sy;
            const float xf = (u * (1.0f / 120.0f) + 1.0f) * 63.5f;
            const float x0f = floorf(xf);
            const float wx1 = xf - x0f;
            const float wx0 = 1.0f - wx1;
            const int ix0 = (int)x0f;
            const int ix1 = ix0 + 1;
            const float fx0 = (ix0 >= 0 && ix0 < IMG) ? 1.0f : 0.0f;
            const float fx1 = (ix1 >= 0 && ix1 < IMG) ? 1.0f : 0.0f;
            const int x0c = min(max(ix0, 0), IMG - 1);
            const int x1c = min(max(ix1, 0), IMG - 1);

            const float w00 = wx0 * wy0 * fx0 * fy0;
            const float w01 = wx1 * wy0 * fx1 * fy0;
            const float w10 = wx0 * wy1 * fx0 * fy1;
            const float w11 = wx1 * wy1 * fx1 * fy1;

            const f4 v00 = *(const f4*)(base0 + (size_t)x0c * NC);
            const f4 v01 = *(const f4*)(base0 + (size_t)x1c * NC);
            const f4 v10 = *(const f4*)(base1 + (size_t)x0c * NC);
            const f4 v11 = *(const f4*)(base1 + (size_t)x1c * NC);

            acc[j] += v00 * w00 + v01 * w01 + v10 * w10 + v11 * w11;
        }
    }

    // LDS transpose so the global store is w-contiguous per channel
    __shared__ float sacc[NC][NW + 1];
#pragma unroll
    for (int j = 0; j < 2; ++j)
#pragma unroll
        for (int ci = 0; ci < 4; ++ci)
            sacc[c4 * 4 + ci][w0 + j * 32] = acc[j][ci] * 0.125f;
    __syncthreads();

#pragma unroll
    for (int k = 0; k < NC * NW; k += 256) {
        const int flat = k + threadIdx.x;
        const int ch = flat >> 6;
        const int w  = flat & 63;
        out[(((size_t)ch * ND + d) * NH + h) * NW + w] = sacc[ch][w];
    }
}

// ---------------- Fallback (round-1 kernel) if d_ws is too small ----------------
__global__ __launch_bounds__(256) void backproj_kernel(
    const float* __restrict__ x_rays, const float* __restrict__ angles,
    float* __restrict__ out)
{
    const int w  = threadIdx.x & 63;
    const int cg = threadIdx.x >> 6;
    const int h  = blockIdx.x & 63;
    const int d  = blockIdx.x >> 6;
    const float step = 240.0f / 63.0f;
    const float zd = -120.0f + d * step;
    const float yf = (zd * (1.0f / 120.0f) + 1.0f) * 63.5f;
    const float y0f = floorf(yf);
    const float wy1 = yf - y0f, wy0 = 1.0f - wy1;
    const int iy0 = (int)y0f, iy1 = iy0 + 1;
    const float fy0 = (iy0 >= 0 && iy0 < IMG) ? 1.0f : 0.0f;
    const float fy1 = (iy1 >= 0 && iy1 < IMG) ? 1.0f : 0.0f;
    const int r0 = min(max(iy0, 0), IMG - 1) * IMG;
    const int r1 = min(max(iy1, 0), IMG - 1) * IMG;
    const float xw = -120.0f + w * step;
    const float yh = -120.0f + h * step;
    float acc[8];
#pragma unroll
    for (int i = 0; i < 8; ++i) acc[i] = 0.0f;
#pragma unroll
    for (int v = 0; v < NV; ++v) {
        float s, c;
        sincosf(angles[v], &s, &c);
        const float u = c * xw - s * yh;
        const float xf = (u * (1.0f / 120.0f) + 1.0f) * 63.5f;
        const float x0f = floorf(xf);
        const float wx1 = xf - x0f, wx0 = 1.0f - wx1;
        const int ix0 = (int)x0f, ix1 = ix0 + 1;
        const float fx0 = (ix0 >= 0 && ix0 < IMG) ? 1.0f : 0.0f;
        const float fx1 = (ix1 >= 0 && ix1 < IMG) ? 1.0f : 0.0f;
        const int x0c = min(max(ix0, 0), IMG - 1);
        const int x1c = min(max(ix1, 0), IMG - 1);
        const float w00 = wx0 * wy0 * fx0 * fy0;
        const float w01 = wx1 * wy0 * fx1 * fy0;
        const float w10 = wx0 * wy1 * fx0 * fy1;
        const float w11 = wx1 * wy1 * fx1 * fy1;
        const float* img = x_rays + (size_t)v * NC * IMG * IMG + (size_t)(cg * 8) * IMG * IMG;
#pragma unroll
        for (int ci = 0; ci < 8; ++ci) {
            const float* p = img + (size_t)ci * IMG * IMG;
            acc[ci] += p[r0 + x0c] * w00 + p[r0 + x1c] * w01
                     + p[r1 + x0c] * w10 + p[r1 + x1c] * w11;
        }
    }
#pragma unroll
    for (int ci = 0; ci < 8; ++ci) {
        const int ch = cg * 8 + ci;
        out[(((size_t)ch * ND + d) * NH + h) * NW + w] = acc[ci] * 0.125f;
    }
}

extern "C" void kernel_launch(void* const* d_in, const int* in_sizes, int n_in,
                              void* d_out, int out_size, void* d_ws, size_t ws_size,
                              hipStream_t stream) {
    const float* x_rays = (const float*)d_in[0];  // [1,8,32,128,128]
    const float* angles = (const float*)d_in[1];  // [1,8]
    float* out = (float*)d_out;                   // [1,32,64,64,64]

    const size_t repack_bytes = (size_t)NV * IMG * IMG * NC * sizeof(float);
    if (ws_size >= repack_bytes) {
        float* imgs_cl = (float*)d_ws;
        repack_kernel<<<NV * IMG, 256, 0, stream>>>(x_rays, imgs_cl);
        backproj_cl_kernel<<<ND * NH, 256, 0, stream>>>(imgs_cl, angles, out);
    } else {
        backproj_kernel<<<ND * NH, 256, 0, stream>>>(x_rays, angles, out);
    }
}

// Round 3
// 115.215 us; speedup vs baseline: 3.1175x; 3.1175x over previous
//
#include <hip/hip_runtime.h>
#include <math.h>

#define NV   8
#define NC   32
#define ND   64
#define NH   64
#define NW   64
#define IMG  128

using f4 = __attribute__((ext_vector_type(4))) float;

// ---------------- Kernel 1: repack [V,C,Y,X] -> [V,Y,X,C] ----------------
__global__ __launch_bounds__(256) void repack_kernel(
    const float* __restrict__ in, float* __restrict__ out)
{
    __shared__ float tile[IMG][NC + 1];          // 128 x 33 floats, pad kills conflicts
    const int vy = blockIdx.x;                   // v*128 + y
    const int v  = vy >> 7;
    const int y  = vy & 127;
    const float* src = in + (size_t)v * NC * IMG * IMG + (size_t)y * IMG;

#pragma unroll
    for (int k = 0; k < NC * IMG; k += 256) {    // read coalesced along x
        const int flat = k + threadIdx.x;
        const int x = flat & (IMG - 1);
        const int c = flat >> 7;
        tile[x][c] = src[(size_t)c * IMG * IMG + x];
    }
    __syncthreads();

    float* dst = out + (size_t)vy * IMG * NC;    // [x][c] contiguous
#pragma unroll
    for (int k = 0; k < NC * IMG; k += 256) {    // write coalesced along c-then-x
        const int flat = k + threadIdx.x;
        const int c = flat & (NC - 1);
        const int x = flat >> 5;
        dst[flat] = tile[x][c];
    }
}

// ---------------- Kernel 2: back-projection, channel-last gathers ----------------
// 512 threads: tid = w*8 + c4. Each thread: one voxel column position (d,h,w),
// 4 channels (c4*4 .. c4*4+3), single f4 accumulator -> low register pressure.
__global__ __launch_bounds__(512) void backproj_cl_kernel(
    const float* __restrict__ imgs,    // [V, Y, X, C] channel-last (in d_ws)
    const float* __restrict__ angles,  // [V]
    float* __restrict__ out)           // [C, D, H, W]
{
    __shared__ float ssin[NV], scos[NV];
    __shared__ float sacc[NC][NW + 1];

    const int tid = threadIdx.x;
    if (tid < NV) {
        float s, c;
        sincosf(angles[tid], &s, &c);
        ssin[tid] = s; scos[tid] = c;
    }

    const int c4 = tid & 7;            // channel quad: channels c4*4 .. c4*4+3
    const int w  = tid >> 3;           // 0..63
    const int h  = blockIdx.x & 63;
    const int d  = blockIdx.x >> 6;

    const float step = 240.0f / 63.0f;

    // y side: depends only on d
    const float zd  = -120.0f + d * step;
    const float yf  = (zd * (1.0f / 120.0f) + 1.0f) * 63.5f;
    const float y0f = floorf(yf);
    const float wy1 = yf - y0f;
    const float wy0 = 1.0f - wy1;
    const int iy0 = (int)y0f;
    const int iy1 = iy0 + 1;
    const float fy0 = (iy0 >= 0 && iy0 < IMG) ? 1.0f : 0.0f;
    const float fy1 = (iy1 >= 0 && iy1 < IMG) ? 1.0f : 0.0f;
    const int r0 = min(max(iy0, 0), IMG - 1);
    const int r1 = min(max(iy1, 0), IMG - 1);

    const float xw = -120.0f + w * step;
    const float yh = -120.0f + h * step;

    __syncthreads();

    f4 acc = (f4)0.0f;

#pragma unroll
    for (int v = 0; v < NV; ++v) {
        const float s = ssin[v];
        const float c = scos[v];

        const float u  = c * xw - s * yh;
        const float xf = (u * (1.0f / 120.0f) + 1.0f) * 63.5f;
        const float x0f = floorf(xf);
        const float wx1 = xf - x0f;
        const float wx0 = 1.0f - wx1;
        const int ix0 = (int)x0f;
        const int ix1 = ix0 + 1;
        const float fx0 = (ix0 >= 0 && ix0 < IMG) ? 1.0f : 0.0f;
        const float fx1 = (ix1 >= 0 && ix1 < IMG) ? 1.0f : 0.0f;
        const int x0c = min(max(ix0, 0), IMG - 1);
        const int x1c = min(max(ix1, 0), IMG - 1);

        const float w00 = wx0 * wy0 * fx0 * fy0;
        const float w01 = wx1 * wy0 * fx1 * fy0;
        const float w10 = wx0 * wy1 * fx0 * fy1;
        const float w11 = wx1 * wy1 * fx1 * fy1;

        const float* base0 = imgs + (((size_t)v * IMG + r0) * IMG) * NC + c4 * 4;
        const float* base1 = imgs + (((size_t)v * IMG + r1) * IMG) * NC + c4 * 4;

        const f4 v00 = *(const f4*)(base0 + (size_t)x0c * NC);
        const f4 v01 = *(const f4*)(base0 + (size_t)x1c * NC);
        const f4 v10 = *(const f4*)(base1 + (size_t)x0c * NC);
        const f4 v11 = *(const f4*)(base1 + (size_t)x1c * NC);

        acc += v00 * w00 + v01 * w01 + v10 * w10 + v11 * w11;
    }

    // LDS transpose so the global store is w-contiguous per channel
#pragma unroll
    for (int ci = 0; ci < 4; ++ci)
        sacc[c4 * 4 + ci][w] = acc[ci] * 0.125f;
    __syncthreads();

#pragma unroll
    for (int k = 0; k < NC * NW; k += 512) {
        const int flat = k + tid;
        const int ch = flat >> 6;
        const int ww = flat & 63;
        out[(((size_t)ch * ND + d) * NH + h) * NW + ww] = sacc[ch][ww];
    }
}

// ---------------- Fallback (round-1 kernel) if d_ws is too small ----------------
__global__ __launch_bounds__(256) void backproj_kernel(
    const float* __restrict__ x_rays, const float* __restrict__ angles,
    float* __restrict__ out)
{
    const int w  = threadIdx.x & 63;
    const int cg = threadIdx.x >> 6;
    const int h  = blockIdx.x & 63;
    const int d  = blockIdx.x >> 6;
    const float step = 240.0f / 63.0f;
    const float zd = -120.0f + d * step;
    const float yf = (zd * (1.0f / 120.0f) + 1.0f) * 63.5f;
    const float y0f = floorf(yf);
    const float wy1 = yf - y0f, wy0 = 1.0f - wy1;
    const int iy0 = (int)y0f, iy1 = iy0 + 1;
    const float fy0 = (iy0 >= 0 && iy0 < IMG) ? 1.0f : 0.0f;
    const float fy1 = (iy1 >= 0 && iy1 < IMG) ? 1.0f : 0.0f;
    const int r0 = min(max(iy0, 0), IMG - 1) * IMG;
    const int r1 = min(max(iy1, 0), IMG - 1) * IMG;
    const float xw = -120.0f + w * step;
    const float yh = -120.0f + h * step;
    float acc[8];
#pragma unroll
    for (int i = 0; i < 8; ++i) acc[i] = 0.0f;
#pragma unroll
    for (int v = 0; v < NV; ++v) {
        float s, c;
        sincosf(angles[v], &s, &c);
        const float u = c * xw - s * yh;
        const float xf = (u * (1.0f / 120.0f) + 1.0f) * 63.5f;
        const float x0f = floorf(xf);
        const float wx1 = xf - x0f, wx0 = 1.0f - wx1;
        const int ix0 = (int)x0f, ix1 = ix0 + 1;
        const float fx0 = (ix0 >= 0 && ix0 < IMG) ? 1.0f : 0.0f;
        const float fx1 = (ix1 >= 0 && ix1 < IMG) ? 1.0f : 0.0f;
        const int x0c = min(max(ix0, 0), IMG - 1);
        const int x1c = min(max(ix1, 0), IMG - 1);
        const float w00 = wx0 * wy0 * fx0 * fy0;
        const float w01 = wx1 * wy0 * fx1 * fy0;
        const float w10 = wx0 * wy1 * fx0 * fy1;
        const float w11 = wx1 * wy1 * fx1 * fy1;
        const float* img = x_rays + (size_t)v * NC * IMG * IMG + (size_t)(cg * 8) * IMG * IMG;
#pragma unroll
        for (int ci = 0; ci < 8; ++ci) {
            const float* p = img + (size_t)ci * IMG * IMG;
            acc[ci] += p[r0 + x0c] * w00 + p[r0 + x1c] * w01
                     + p[r1 + x0c] * w10 + p[r1 + x1c] * w11;
        }
    }
#pragma unroll
    for (int ci = 0; ci < 8; ++ci) {
        const int ch = cg * 8 + ci;
        out[(((size_t)ch * ND + d) * NH + h) * NW + w] = acc[ci] * 0.125f;
    }
}

extern "C" void kernel_launch(void* const* d_in, const int* in_sizes, int n_in,
                              void* d_out, int out_size, void* d_ws, size_t ws_size,
                              hipStream_t stream) {
    const float* x_rays = (const float*)d_in[0];  // [1,8,32,128,128]
    const float* angles = (const float*)d_in[1];  // [1,8]
    float* out = (float*)d_out;                   // [1,32,64,64,64]

    const size_t repack_bytes = (size_t)NV * IMG * IMG * NC * sizeof(float);
    if (ws_size >= repack_bytes) {
        float* imgs_cl = (float*)d_ws;
        repack_kernel<<<NV * IMG, 256, 0, stream>>>(x_rays, imgs_cl);
        backproj_cl_kernel<<<ND * NH, 512, 0, stream>>>(imgs_cl, angles, out);
    } else {
        backproj_kernel<<<ND * NH, 256, 0, stream>>>(x_rays, angles, out);
    }
}

// Round 4
// 88.574 us; speedup vs baseline: 4.0552x; 1.3008x over previous
//
#include <hip/hip_runtime.h>
#include <math.h>

#define NV   8
#define NC   32
#define ND   64
#define NH   64
#define NW   64
#define IMG  128
#define CG   16      // channels per block (2 blocks cover 32)
#define HT   16      // h rows per block (4 blocks cover 64)

using f4 = __attribute__((ext_vector_type(4))) float;

// Swizzled LDS layout for the y-lerped rows: per view-plane, 128 x-positions
// x 4 channel-halves (4ch each) = 512 16B-units. XOR-mix x bits into the
// bank-group bits so that gather lanes (x stride ~2*cos, c fixed) spread
// across all 8 4-bank groups. Bijective: bits>=3 of unit give x>>1; bit2
// recovers x0 (= bit2 ^ x3 ^ x5); low 2 bits then give chalf.
__device__ __forceinline__ int lds_unit(int x, int chalf) {
    return ((x << 2) | chalf) ^ (((x >> 1) ^ (x >> 3)) & 7);
}

__global__ __launch_bounds__(256) void backproj_fused(
    const float* __restrict__ x_rays,   // [8,32,128,128]
    const float* __restrict__ angles,   // [8]
    float* __restrict__ out)            // [32,64,64,64]
{
    const int bid = blockIdx.x;
    const int d   = bid >> 3;          // d outer: blocks sharing d share image rows (L2)
    const int cg  = (bid >> 2) & 1;
    const int hq  = bid & 3;
    const int c0  = cg * CG;

    __shared__ float rowbuf[NV * IMG * CG];   // 64 KB, swizzled [v][x][c16]
    __shared__ float ssin[NV], scos[NV];

    const int tid = threadIdx.x;
    if (tid < NV) {
        float s, c;
        sincosf(angles[tid], &s, &c);
        ssin[tid] = s; scos[tid] = c;
    }

    // ---- y side (depends only on d): yf = K*d exactly, K = 127/63 ----
    const float K   = 127.0f / 63.0f;
    const float yf  = K * (float)d;
    const float y0f = floorf(yf);
    const int   iy0 = (int)y0f;            // always in [0,127]
    const int   iy1 = iy0 + 1;
    float wy1 = yf - y0f;
    const float wy0 = 1.0f - wy1;
    if (iy1 > IMG - 1) wy1 = 0.0f;         // zeros padding on y1 corner
    const int r0 = iy0;
    const int r1 = min(iy1, IMG - 1);
    // fold the 1/8 view-mean into the y weights (linear, safe)
    const float wy0f = wy0 * 0.125f;
    const float wy1f = wy1 * 0.125f;

    // ---- stage y-lerped rows into swizzled LDS ----
    // 8v * 16c * 32 xg(f4) = 4096 f4 elements; lanes contiguous in xg -> coalesced
#pragma unroll
    for (int it = 0; it < 16; ++it) {
        const int flat = it * 256 + tid;       // 0..4095
        const int xg = flat & 31;
        const int c  = (flat >> 5) & 15;
        const int v  = flat >> 9;
        const float* plane = x_rays + ((size_t)(v * NC + c0 + c) * IMG) * IMG;
        const f4 a = *(const f4*)(plane + r0 * IMG + xg * 4);
        const f4 b = *(const f4*)(plane + r1 * IMG + xg * 4);
        const f4 val = a * wy0f + b * wy1f;
        const int chalf = c >> 2;
        const int csub  = c & 3;
        const int vbase = v * (IMG * CG);
#pragma unroll
        for (int j = 0; j < 4; ++j) {
            const int x = xg * 4 + j;
            rowbuf[vbase + lds_unit(x, chalf) * 4 + csub] = val[j];
        }
    }
    __syncthreads();

    // ---- compute ----
    const int w     = tid & 63;
    const int hlane = tid >> 6;

    float sv[NV], cv[NV], tv[NV];
    const float Kw = K * (float)w;
#pragma unroll
    for (int v = 0; v < NV; ++v) {
        const float s = ssin[v], c = scos[v];
        sv[v] = s; cv[v] = c;
        // xf = 63.5*(1 - c + s) + K*(c*w - s*h) = tv - s*Kh
        tv[v] = 63.5f * (1.0f - c + s) + c * Kw;
    }

    const size_t ostride_c = (size_t)ND * NH * NW;   // 262144

#pragma unroll
    for (int hi = 0; hi < 4; ++hi) {
        const int h = hq * HT + hi * 4 + hlane;
        const float Kh = K * (float)h;

        f4 acc[4];
#pragma unroll
        for (int k = 0; k < 4; ++k) acc[k] = (f4)0.0f;

#pragma unroll
        for (int v = 0; v < NV; ++v) {
            const float xf  = tv[v] - sv[v] * Kh;
            const float x0f = floorf(xf);
            const int   ix0 = (int)x0f;
            float wx1 = xf - x0f;
            float wx0 = 1.0f - wx1;
            if (ix0 < 0 || ix0 > IMG - 1)      wx0 = 0.0f;  // x0 corner validity
            if (ix0 < -1 || ix0 > IMG - 2)     wx1 = 0.0f;  // x1 corner validity
            const int x0c = min(max(ix0, 0), IMG - 1);
            const int x1c = min(max(ix0 + 1, 0), IMG - 1);

            const int vbase = v * (IMG * CG);
            const int a0 = vbase + lds_unit(x0c, 0) * 4;   // float index, 16B aligned
            const int a1 = vbase + lds_unit(x1c, 0) * 4;

#pragma unroll
            for (int k = 0; k < 4; ++k) {
                // chalf=k lives in unit bits 1:0 -> float-index bits 3:2 (XOR)
                const f4 p0 = *(const f4*)&rowbuf[a0 ^ (k << 2)];
                const f4 p1 = *(const f4*)&rowbuf[a1 ^ (k << 2)];
                acc[k] += p0 * wx0 + p1 * wx1;
            }
        }

        // store: lanes contiguous in w per channel -> coalesced 256B chunks
        float* op = out + (size_t)c0 * ostride_c + (size_t)d * NH * NW
                        + (size_t)h * NW + w;
#pragma unroll
        for (int k = 0; k < 4; ++k) {
#pragma unroll
            for (int j = 0; j < 4; ++j) {
                op[(size_t)(k * 4 + j) * ostride_c] = acc[k][j];
            }
        }
    }
}

extern "C" void kernel_launch(void* const* d_in, const int* in_sizes, int n_in,
                              void* d_out, int out_size, void* d_ws, size_t ws_size,
                              hipStream_t stream) {
    const float* x_rays = (const float*)d_in[0];  // [1,8,32,128,128]
    const float* angles = (const float*)d_in[1];  // [1,8]
    float* out = (float*)d_out;                   // [1,32,64,64,64]

    // grid: 64 d x 2 channel-halves x 4 h-quarters = 512 blocks
    backproj_fused<<<ND * 2 * 4, 256, 0, stream>>>(x_rays, angles, out);
}

// Round 5
// 85.263 us; speedup vs baseline: 4.2126x; 1.0388x over previous
//
#include <hip/hip_runtime.h>
#include <math.h>

#define NV   8
#define NC   32
#define ND   64
#define NH   64
#define NW   64
#define IMG  128
#define CG   8      // channels per block (4 blocks cover 32)
#define HT   16     // h rows per block (4 blocks cover 64)

typedef _Float16 h2 __attribute__((ext_vector_type(2)));
typedef _Float16 h8 __attribute__((ext_vector_type(8)));

struct H2x4 { h2 q0, q1, q2, q3; };

// LDS unit = one x position, 8 channels f16 = 16B. Bank-group = unit&7.
// XOR x's bits 3..5 into bits 0..2: gather lanes (x stride ~2*cos) spread
// across groups with <=2-way aliasing (free); bijective within each v-plane.
__device__ __forceinline__ int swz(int x) { return x ^ ((x >> 3) & 7); }

__global__ __launch_bounds__(256) void backproj_fused(
    const float* __restrict__ x_rays,   // [8,32,128,128]
    const float* __restrict__ angles,   // [8]
    float* __restrict__ out)            // [32,64,64,64]
{
    const int bid = blockIdx.x;
    const int d   = bid >> 4;          // 64 ; blocks sharing d share image rows
    const int cg  = (bid >> 2) & 3;    // 4 channel groups of 8
    const int hq  = bid & 3;           // 4 h-quarters of 16
    const int c0  = cg * CG;

    __shared__ h8    rowbuf[NV * IMG];   // 16 KB, swizzled [v][x] -> 8ch f16
    __shared__ float ssin[NV], scos[NV];

    const int tid = threadIdx.x;
    if (tid < NV) {
        float s, c;
        sincosf(angles[tid], &s, &c);
        ssin[tid] = s; scos[tid] = c;
    }

    // ---- y side (depends only on d): yf = K*d, K = 127/63 ----
    const float K   = 127.0f / 63.0f;
    const float yf  = K * (float)d;
    const float y0f = floorf(yf);
    const int   iy0 = (int)y0f;            // in [0,127]
    float wy1 = yf - y0f;
    const float wy0 = 1.0f - wy1;
    const int r0 = iy0;
    int r1 = iy0 + 1;
    if (r1 > IMG - 1) { r1 = IMG - 1; wy1 = 0.0f; }   // zeros padding on y1
    const float wy0f = wy0 * 0.125f;       // fold 1/8 view-mean
    const float wy1f = wy1 * 0.125f;

    // ---- stage y-lerped rows into swizzled f16 LDS ----
    // 8v * 128x units; lanes x-contiguous -> coalesced 256B global reads,
    // one ds_write_b128 per unit.
    const int sx  = tid & 127;
    const int svh = tid >> 7;              // 0..1
#pragma unroll
    for (int it = 0; it < 4; ++it) {
        const int v = it * 2 + svh;
        const float* pl = x_rays + (size_t)(v * NC + c0) * (IMG * IMG);
        h8 val;
#pragma unroll
        for (int cc = 0; cc < 8; ++cc) {
            const float* p = pl + (size_t)cc * (IMG * IMG);
            const float a = p[r0 * IMG + sx] * wy0f + p[r1 * IMG + sx] * wy1f;
            val[cc] = (_Float16)a;         // RNE
        }
        rowbuf[v * IMG + swz(sx)] = val;
    }
    __syncthreads();

    // ---- compute ----
    const int w  = tid & 63;
    const int hl = tid >> 6;               // 0..3

    float sv[NV], tv[NV];
    const float Kw = K * (float)w;
#pragma unroll
    for (int v = 0; v < NV; ++v) {
        const float s = ssin[v], c = scos[v];
        sv[v] = K * s;
        // xf = 63.5*(1 - c + s) + K*(c*w - s*h)
        tv[v] = 63.5f * (1.0f - c + s) + c * Kw;
    }

    const size_t cs = (size_t)ND * NH * NW;   // 262144

#pragma unroll
    for (int hi = 0; hi < 4; ++hi) {
        const int h = hq * HT + hi * 4 + hl;
        const float hh = (float)h;

        h2 acc0 = {(_Float16)0, (_Float16)0};
        h2 acc1 = acc0, acc2 = acc0, acc3 = acc0;

#pragma unroll
        for (int v = 0; v < NV; ++v) {
            const float xf  = tv[v] - sv[v] * hh;
            const float x0f = floorf(xf);
            const int   ix0 = (int)x0f;
            float wx1 = xf - x0f;
            float wx0 = 1.0f - wx1;
            if (ix0 < 0 || ix0 > IMG - 1)      wx0 = 0.0f;  // x0 corner valid?
            if (ix0 < -1 || ix0 > IMG - 2)     wx1 = 0.0f;  // x1 corner valid?
            const int x0c = min(max(ix0, 0), IMG - 1);
            const int x1c = min(max(ix0 + 1, 0), IMG - 1);

            const h8 P0 = rowbuf[v * IMG + swz(x0c)];   // ds_read_b128
            const h8 P1 = rowbuf[v * IMG + swz(x1c)];   // ds_read_b128

            const _Float16 w0h = (_Float16)wx0;
            const _Float16 w1h = (_Float16)wx1;
            const h2 w0 = {w0h, w0h};
            const h2 w1 = {w1h, w1h};

            const H2x4 a = __builtin_bit_cast(H2x4, P0);
            const H2x4 b = __builtin_bit_cast(H2x4, P1);
            acc0 += a.q0 * w0 + b.q0 * w1;   // v_pk_fma_f16
            acc1 += a.q1 * w0 + b.q1 * w1;
            acc2 += a.q2 * w0 + b.q2 * w1;
            acc3 += a.q3 * w0 + b.q3 * w1;
        }

        // store: lanes contiguous in w -> coalesced 256B per wave-store
        float* op = out + (size_t)c0 * cs + ((size_t)d * NH + h) * NW + w;
        op[0 * cs] = (float)acc0[0]; op[1 * cs] = (float)acc0[1];
        op[2 * cs] = (float)acc1[0]; op[3 * cs] = (float)acc1[1];
        op[4 * cs] = (float)acc2[0]; op[5 * cs] = (float)acc2[1];
        op[6 * cs] = (float)acc3[0]; op[7 * cs] = (float)acc3[1];
    }
}

extern "C" void kernel_launch(void* const* d_in, const int* in_sizes, int n_in,
                              void* d_out, int out_size, void* d_ws, size_t ws_size,
                              hipStream_t stream) {
    const float* x_rays = (const float*)d_in[0];  // [1,8,32,128,128]
    const float* angles = (const float*)d_in[1];  // [1,8]
    float* out = (float*)d_out;                   // [1,32,64,64,64]

    // grid: 64 d x 4 channel-groups x 4 h-quarters = 1024 blocks
    backproj_fused<<<ND * 4 * 4, 256, 0, stream>>>(x_rays, angles, out);
}

// Round 6
// 82.193 us; speedup vs baseline: 4.3700x; 1.0373x over previous
//
#include <hip/hip_runtime.h>
#include <math.h>

#define NV   8
#define NC   32
#define ND   64
#define NH   64
#define NW   64
#define IMG  128
#define CG   8      // channels per block (4 cg blocks cover 32)
#define HT   32     // h rows per block (2 hq blocks cover 64)

typedef _Float16 h2 __attribute__((ext_vector_type(2)));
typedef _Float16 h8 __attribute__((ext_vector_type(8)));

struct H2x4 { h2 q0, q1, q2, q3; };

// LDS unit = one x position, 8 channels f16 = 16B. Bank-group = unit&7.
// XOR x bits 3..5 into bits 0..2: gather lanes (x stride ~2*cos) spread
// across groups with <=2-way aliasing (free); bijective within each v-plane.
__device__ __forceinline__ int swz(int x) { return x ^ ((x >> 3) & 7); }

__global__ __launch_bounds__(512) void backproj_fused(
    const float* __restrict__ x_rays,   // [8,32,128,128]
    const float* __restrict__ angles,   // [8]
    float* __restrict__ out)            // [32,64,64,64]
{
    const int bid = blockIdx.x;
    const int d   = bid >> 3;          // 64 ; blocks sharing d share image rows
    const int cg  = (bid >> 1) & 3;    // 4 channel groups of 8
    const int hq  = bid & 1;           // 2 h-halves of 32
    const int c0  = cg * CG;

    __shared__ h8    rowbuf[NV * IMG];   // 16 KB, swizzled [v][x] -> 8ch f16
    __shared__ float ssin[NV], scos[NV];

    const int tid = threadIdx.x;
    if (tid < NV) {
        float s, c;
        sincosf(angles[tid], &s, &c);
        ssin[tid] = s; scos[tid] = c;
    }

    // ---- y side (depends only on d): yf = K*d, K = 127/63 ----
    const float K   = 127.0f / 63.0f;
    const float yf  = K * (float)d;
    const float y0f = floorf(yf);
    const int   iy0 = (int)y0f;            // in [0,127]
    float wy1 = yf - y0f;
    const float wy0 = 1.0f - wy1;
    const int r0 = iy0;
    int r1 = iy0 + 1;
    if (r1 > IMG - 1) { r1 = IMG - 1; wy1 = 0.0f; }   // zeros padding on y1
    const float wy0f = wy0 * 0.125f;       // fold 1/8 view-mean
    const float wy1f = wy1 * 0.125f;

    // ---- stage y-lerped rows into swizzled f16 LDS ----
    // 1024 units (8v x 128x); 512 threads -> 2 units each (v and v+4),
    // lanes x-contiguous -> coalesced 512B row reads, one ds_write_b128/unit.
    const int sx = tid & 127;
    const int sv = tid >> 7;               // 0..3
#pragma unroll
    for (int k = 0; k < 2; ++k) {
        const int v = sv + k * 4;
        const float* pl = x_rays + (size_t)(v * NC + c0) * (IMG * IMG);
        h8 val;
#pragma unroll
        for (int cc = 0; cc < 8; ++cc) {
            const float* p = pl + (size_t)cc * (IMG * IMG);
            const float a = fmaf(p[r0 * IMG + sx], wy0f, p[r1 * IMG + sx] * wy1f);
            val[cc] = (_Float16)a;         // RNE
        }
        rowbuf[v * IMG + swz(sx)] = val;
    }
    __syncthreads();

    // ---- compute ----
    const int w  = tid & 63;
    const int hl = tid >> 6;               // 0..7
    const int h0 = hq * HT + hl;           // first h; hi steps h by +8

    float xfv[NV], dxv[NV];
    const float Kw = K * (float)w;
#pragma unroll
    for (int v = 0; v < NV; ++v) {
        const float s = ssin[v], c = scos[v];
        // xf(h) = 63.5*(1 - c + s) + K*(c*w - s*h); step h by 8 per hi iter
        xfv[v] = fmaf(c, Kw, fmaf(-K * s, (float)h0, 63.5f * (1.0f - c + s)));
        dxv[v] = -8.0f * K * s;
    }

    const size_t cs = (size_t)ND * NH * NW;   // 262144

#pragma unroll
    for (int hi = 0; hi < 4; ++hi) {
        const int h = h0 + hi * 8;

        h2 acc0 = {(_Float16)0, (_Float16)0};
        h2 acc1 = acc0, acc2 = acc0, acc3 = acc0;

#pragma unroll
        for (int v = 0; v < NV; ++v) {
            const float xf  = xfv[v];
            xfv[v] = xf + dxv[v];              // incremental update for next hi
            const float x0f = floorf(xf);
            const int   ix0 = (int)x0f;
            float wx1 = xf - x0f;
            float wx0 = 1.0f - wx1;
            // corner validity via single unsigned compares
            if ((unsigned)ix0 > (unsigned)(IMG - 1))       wx0 = 0.0f;
            if ((unsigned)(ix0 + 1) > (unsigned)(IMG - 1)) wx1 = 0.0f;
            // "clamp" via &127: only differs from true clamp when the
            // corresponding weight is already zero -> value irrelevant.
            const int x0c = ix0 & 127;
            const int x1c = (ix0 + 1) & 127;

            const h8 P0 = rowbuf[v * IMG + swz(x0c)];   // ds_read_b128
            const h8 P1 = rowbuf[v * IMG + swz(x1c)];   // ds_read_b128

            const _Float16 w0h = (_Float16)wx0;
            const _Float16 w1h = (_Float16)wx1;
            const h2 w0 = {w0h, w0h};
            const h2 w1 = {w1h, w1h};

            const H2x4 a = __builtin_bit_cast(H2x4, P0);
            const H2x4 b = __builtin_bit_cast(H2x4, P1);
            acc0 += a.q0 * w0 + b.q0 * w1;   // v_pk_fma_f16
            acc1 += a.q1 * w0 + b.q1 * w1;
            acc2 += a.q2 * w0 + b.q2 * w1;
            acc3 += a.q3 * w0 + b.q3 * w1;
        }

        // store: lanes contiguous in w -> coalesced 256B per wave-store
        float* op = out + (size_t)c0 * cs + ((size_t)d * NH + h) * NW + w;
        op[0 * cs] = (float)acc0[0]; op[1 * cs] = (float)acc0[1];
        op[2 * cs] = (float)acc1[0]; op[3 * cs] = (float)acc1[1];
        op[4 * cs] = (float)acc2[0]; op[5 * cs] = (float)acc2[1];
        op[6 * cs] = (float)acc3[0]; op[7 * cs] = (float)acc3[1];
    }
}

extern "C" void kernel_launch(void* const* d_in, const int* in_sizes, int n_in,
                              void* d_out, int out_size, void* d_ws, size_t ws_size,
                              hipStream_t stream) {
    const float* x_rays = (const float*)d_in[0];  // [1,8,32,128,128]
    const float* angles = (const float*)d_in[1];  // [1,8]
    float* out = (float*)d_out;                   // [1,32,64,64,64]

    // grid: 64 d x 4 channel-groups x 2 h-halves = 512 blocks x 512 threads
    backproj_fused<<<ND * 4 * 2, 512, 0, stream>>>(x_rays, angles, out);
}

// Round 8
// 78.219 us; speedup vs baseline: 4.5920x; 1.0508x over previous
//
#include <hip/hip_runtime.h>
#include <math.h>

#define NV   8
#define NC   32
#define ND   64
#define NH   64
#define NW   64
#define IMG  128
#define CG   8      // channels per block (4 cg blocks cover 32)

typedef _Float16 h2 __attribute__((ext_vector_type(2)));
typedef _Float16 h8 __attribute__((ext_vector_type(8)));

struct H2x4 { h2 q0, q1, q2, q3; };

// LDS unit = one x position, 8 channels f16 = 16B. Bank-group = unit&7.
// XOR x bits 3..5 into bits 0..2: gather lanes (x stride ~2*cos) spread
// across groups with <=2-way aliasing (free); bijective within each v-plane.
__device__ __forceinline__ int swz(int x) { return x ^ ((x >> 3) & 7); }

__global__ __launch_bounds__(1024) void backproj_fused(
    const float* __restrict__ x_rays,   // [8,32,128,128]
    const float* __restrict__ angles,   // [8]
    float* __restrict__ out)            // [32,64,64,64]
{
    const int bid = blockIdx.x;
    const int d   = bid >> 2;          // 0..63
    const int cg  = bid & 3;           // 4 channel groups of 8
    const int c0  = cg * CG;

    __shared__ h8    rowbuf[NV * IMG];   // 16 KB, swizzled [v][x] -> 8ch f16
    __shared__ float ssin[NV], scos[NV];

    const int tid = threadIdx.x;
    if (tid < NV) {
        float s, c;
        sincosf(angles[tid], &s, &c);
        ssin[tid] = s; scos[tid] = c;
    }

    // ---- y side (depends only on d): yf = K*d, K = 127/63 ----
    const float K   = 127.0f / 63.0f;
    const float yf  = K * (float)d;
    const float y0f = floorf(yf);
    const int   iy0 = (int)y0f;            // in [0,127]
    float wy1 = yf - y0f;
    const float wy0 = 1.0f - wy1;
    const int r0 = iy0;
    int r1 = iy0 + 1;
    if (r1 > IMG - 1) { r1 = IMG - 1; wy1 = 0.0f; }   // zeros padding on y1
    const float wy0f = wy0 * 0.125f;       // fold 1/8 view-mean
    const float wy1f = wy1 * 0.125f;

    // ---- stage y-lerped rows into swizzled f16 LDS: 1 unit per thread ----
    {
        const int sx = tid & 127;
        const int sv = tid >> 7;           // 0..7
        const float* pl = x_rays + (size_t)(sv * NC + c0) * (IMG * IMG);
        h8 val;
#pragma unroll
        for (int cc = 0; cc < 8; ++cc) {
            const float* p = pl + (size_t)cc * (IMG * IMG);
            const float a = fmaf(p[r0 * IMG + sx], wy0f, p[r1 * IMG + sx] * wy1f);
            val[cc] = (_Float16)a;         // RNE
        }
        rowbuf[sv * IMG + swz(sx)] = val;
    }
    __syncthreads();

    // ---- compute ----
    const int w  = tid & 63;
    const int hl = tid >> 6;               // 0..15
    const float Kw = K * (float)w;

    float xfv[NV], dxv[NV];
#pragma unroll
    for (int v = 0; v < NV; ++v) {
        const float s = ssin[v], c = scos[v];
        // xf(h) = 63.5*(1 - c + s) + K*(c*w - s*h); h = hl + hi*16
        xfv[v] = fmaf(c, Kw, fmaf(-K * s, (float)hl, 63.5f * (1.0f - c + s)));
        dxv[v] = -16.0f * K * s;
    }

    const size_t cs = (size_t)ND * NH * NW;   // 262144

#pragma unroll
    for (int hi = 0; hi < 4; ++hi) {
        const int h = hl + hi * 16;

        h2 acc0 = {(_Float16)0, (_Float16)0};
        h2 acc1 = acc0, acc2 = acc0, acc3 = acc0;

#pragma unroll
        for (int v = 0; v < NV; ++v) {
            const float xf  = xfv[v];
            xfv[v] = xf + dxv[v];              // incremental update for next hi
            const float x0f = floorf(xf);
            const int   ix0 = (int)x0f;
            float wx1 = xf - x0f;
            float wx0 = 1.0f - wx1;
            // corner validity via single unsigned compares
            if ((unsigned)ix0 > (unsigned)(IMG - 1))       wx0 = 0.0f;
            if ((unsigned)(ix0 + 1) > (unsigned)(IMG - 1)) wx1 = 0.0f;
            // "clamp" via &127: only differs from true clamp when the
            // corresponding weight is already zero -> value irrelevant.
            const int x0c = ix0 & 127;
            const int x1c = (ix0 + 1) & 127;

            const h8 P0 = rowbuf[v * IMG + swz(x0c)];   // ds_read_b128
            const h8 P1 = rowbuf[v * IMG + swz(x1c)];   // ds_read_b128

            const _Float16 w0h = (_Float16)wx0;
            const _Float16 w1h = (_Float16)wx1;
            const h2 w0 = {w0h, w0h};
            const h2 w1 = {w1h, w1h};

            const H2x4 a = __builtin_bit_cast(H2x4, P0);
            const H2x4 b = __builtin_bit_cast(H2x4, P1);
            acc0 += a.q0 * w0 + b.q0 * w1;   // v_pk_fma_f16
            acc1 += a.q1 * w0 + b.q1 * w1;
            acc2 += a.q2 * w0 + b.q2 * w1;
            acc3 += a.q3 * w0 + b.q3 * w1;
        }

        // store: lanes contiguous in w -> coalesced 256B per wave-store.
        // nontemporal: lines were poisoned by the fill on other XCDs; skip
        // cross-XCD ownership churn.
        float* op = out + (size_t)c0 * cs + ((size_t)d * NH + h) * NW + w;
        __builtin_nontemporal_store((float)acc0[0], op + 0 * cs);
        __builtin_nontemporal_store((float)acc0[1], op + 1 * cs);
        __builtin_nontemporal_store((float)acc1[0], op + 2 * cs);
        __builtin_nontemporal_store((float)acc1[1], op + 3 * cs);
        __builtin_nontemporal_store((float)acc2[0], op + 4 * cs);
        __builtin_nontemporal_store((float)acc2[1], op + 5 * cs);
        __builtin_nontemporal_store((float)acc3[0], op + 6 * cs);
        __builtin_nontemporal_store((float)acc3[1], op + 7 * cs);
    }
}

extern "C" void kernel_launch(void* const* d_in, const int* in_sizes, int n_in,
                              void* d_out, int out_size, void* d_ws, size_t ws_size,
                              hipStream_t stream) {
    const float* x_rays = (const float*)d_in[0];  // [1,8,32,128,128]
    const float* angles = (const float*)d_in[1];  // [1,8]
    float* out = (float*)d_out;                   // [1,32,64,64,64]

    // grid: 64 d x 4 channel-groups = 256 blocks x 1024 threads (1 per CU)
    backproj_fused<<<ND * 4, 1024, 0, stream>>>(x_rays, angles, out);
}